// Round 1
// baseline (80.011 us; speedup 1.0000x reference)
//
#include <hip/hip_runtime.h>

static constexpr int BATCH  = 4;
static constexpr int NPTS   = 8192;          // N == M
static constexpr int RCHUNK = 1024;          // ref points staged in LDS per block
static constexpr int NCHUNK = NPTS / RCHUNK; // 8
static constexpr int TPB    = 256;
static constexpr int QPT    = 2;             // query points per thread
static constexpr int QTILE  = TPB * QPT;     // 512
static constexpr int NQTILE = NPTS / QTILE;  // 16
static constexpr int NPROB  = 2 * BATCH;     // (batch, direction) pairs = 8
static constexpr int WSLEN  = NPROB * NPTS;  // 65536 per-query min slots

// ---------------- init: ws min-slots to +inf ----------------
__global__ void cd_init(int* __restrict__ wsmin) {
    int idx = blockIdx.x * blockDim.x + threadIdx.x;   // WSLEN/4 int4 slots
    ((int4*)wsmin)[idx] = make_int4(0x7F800000, 0x7F800000, 0x7F800000, 0x7F800000);
}

// ---------------- main: per-(problem, qtile, refchunk) partial NN min ----------------
__global__ __launch_bounds__(TPB) void cd_chunk(
    const float* __restrict__ gen, const float* __restrict__ train,
    int* __restrict__ wsmin)
{
    __shared__ float4 pts[RCHUNK];           // (x, y, z, yy) per ref point, 16 KB
    const int qtile = blockIdx.x;
    const int chunk = blockIdx.y;
    const int prob  = blockIdx.z;
    const int b = prob >> 1, dir = prob & 1;
    const float* qbase = (dir == 0 ? gen : train) + (size_t)b * NPTS * 3;
    const float* rbase = (dir == 0 ? train : gen) + (size_t)b * NPTS * 3;

    // Stage RCHUNK ref points: each thread loads 12 consecutive floats (= 4 points,
    // float4-aligned since offsets are multiples of 12 floats), computes yy.
    {
        const float4* s4 = (const float4*)(rbase + chunk * (RCHUNK * 3)) + threadIdx.x * 3;
        float4 v0 = s4[0], v1 = s4[1], v2 = s4[2];
        float4* dst = &pts[threadIdx.x * 4];
        dst[0] = make_float4(v0.x, v0.y, v0.z, fmaf(v0.x, v0.x, fmaf(v0.y, v0.y, v0.z * v0.z)));
        dst[1] = make_float4(v0.w, v1.x, v1.y, fmaf(v0.w, v0.w, fmaf(v1.x, v1.x, v1.y * v1.y)));
        dst[2] = make_float4(v1.z, v1.w, v2.x, fmaf(v1.z, v1.z, fmaf(v1.w, v1.w, v2.x * v2.x)));
        dst[3] = make_float4(v2.y, v2.z, v2.w, fmaf(v2.y, v2.y, fmaf(v2.z, v2.z, v2.w * v2.w)));
    }
    __syncthreads();

    const int q0 = qtile * QTILE + threadIdx.x;
    const int q1 = q0 + TPB;
    const float ax0 = qbase[q0*3+0], ay0 = qbase[q0*3+1], az0 = qbase[q0*3+2];
    const float ax1 = qbase[q1*3+0], ay1 = qbase[q1*3+1], az1 = qbase[q1*3+2];

    // running min of (yy - 2*dot); xx added after the loop
    float m0 = 3.4e38f, m1 = 3.4e38f;
    #pragma unroll 4
    for (int j = 0; j < RCHUNK; ++j) {
        float4 r = pts[j];                                   // wave-uniform broadcast read
        float dot0 = fmaf(ax0, r.x, fmaf(ay0, r.y, az0 * r.z));
        float dot1 = fmaf(ax1, r.x, fmaf(ay1, r.y, az1 * r.z));
        m0 = fminf(m0, fmaf(-2.0f, dot0, r.w));
        m1 = fminf(m1, fmaf(-2.0f, dot1, r.w));
    }

    const float qq0 = fmaf(ax0, ax0, fmaf(ay0, ay0, az0 * az0));
    const float qq1 = fmaf(ax1, ax1, fmaf(ay1, ay1, az1 * az1));
    // clamp >= 0 so positive-float int ordering is valid for atomicMin
    float d0 = fmaxf(m0 + qq0, 0.0f);
    float d1 = fmaxf(m1 + qq1, 0.0f);
    atomicMin(&wsmin[prob * NPTS + q0], __float_as_int(d0));
    atomicMin(&wsmin[prob * NPTS + q1], __float_as_int(d1));
}

// ---------------- reduce: sum all mins -> loss ----------------
__global__ void cd_reduce(const int* __restrict__ wsmin, float* __restrict__ out) {
    float s = 0.0f;
    for (int i = threadIdx.x; i < WSLEN; i += 1024)
        s += __int_as_float(wsmin[i]);
    for (int off = 32; off > 0; off >>= 1)
        s += __shfl_down(s, off, 64);
    __shared__ float partial[16];
    const int wave = threadIdx.x >> 6, lane = threadIdx.x & 63;
    if (lane == 0) partial[wave] = s;
    __syncthreads();
    if (threadIdx.x == 0) {
        float t = 0.0f;
        for (int w = 0; w < 16; ++w) t += partial[w];
        out[0] = t * (0.5f / BATCH);
    }
}

extern "C" void kernel_launch(void* const* d_in, const int* in_sizes, int n_in,
                              void* d_out, int out_size, void* d_ws, size_t ws_size,
                              hipStream_t stream) {
    const float* gen   = (const float*)d_in[0];   // gen_points_batch   [4,8192,3] f32
    const float* train = (const float*)d_in[1];   // train_points_dense [4,8192,3] f32
    int*   wsmin = (int*)d_ws;                    // WSLEN ints (256 KB)
    float* out   = (float*)d_out;

    cd_init<<<WSLEN / 4 / 256, 256, 0, stream>>>(wsmin);
    dim3 grid(NQTILE, NCHUNK, NPROB);             // (16, 8, 8) = 1024 blocks
    cd_chunk<<<grid, TPB, 0, stream>>>(gen, train, wsmin);
    cd_reduce<<<1, 1024, 0, stream>>>(wsmin, out);
}

// Round 2
// 57.329 us; speedup vs baseline: 1.3957x; 1.3957x over previous
//
#include <hip/hip_runtime.h>

static constexpr int BATCH  = 4;
static constexpr int NPTS   = 8192;          // N == M
static constexpr int RCHUNK = 512;           // ref points staged in LDS per block
static constexpr int NCHUNK = NPTS / RCHUNK; // 16
static constexpr int TPB    = 512;
static constexpr int QPT    = 4;             // query points per thread
static constexpr int QTILE  = TPB * QPT;     // 2048
static constexpr int NQTILE = NPTS / QTILE;  // 4
static constexpr int NPROB  = 2 * BATCH;     // (batch, direction) pairs = 8
static constexpr int WSLEN  = NPROB * NPTS;  // 65536 per-query min slots

// ---------------- main: per-(problem, qtile, refchunk) partial NN min ----------------
__global__ __launch_bounds__(TPB) void cd_chunk(
    const float* __restrict__ gen, const float* __restrict__ train,
    int* __restrict__ wsmin)
{
    __shared__ float4 pts[RCHUNK];           // (-2x, -2y, -2z, yy) per ref point, 8 KB
    const int qtile = blockIdx.x;
    const int chunk = blockIdx.y;
    const int prob  = blockIdx.z;
    const int b = prob >> 1, dir = prob & 1;
    const float* qbase = (dir == 0 ? gen : train) + (size_t)b * NPTS * 3;
    const float* rbase = (dir == 0 ? train : gen) + (size_t)b * NPTS * 3;

    // Stage RCHUNK ref points, pre-scaled: (-2x,-2y,-2z, x^2+y^2+z^2).
    // Threads 0..127 each load 12 consecutive floats (4 points, float4-aligned).
    if (threadIdx.x < RCHUNK / 4) {
        const float4* s4 = (const float4*)(rbase + chunk * (RCHUNK * 3)) + threadIdx.x * 3;
        float4 v0 = s4[0], v1 = s4[1], v2 = s4[2];
        float4* dst = &pts[threadIdx.x * 4];
        dst[0] = make_float4(-2.0f*v0.x, -2.0f*v0.y, -2.0f*v0.z,
                             fmaf(v0.x, v0.x, fmaf(v0.y, v0.y, v0.z * v0.z)));
        dst[1] = make_float4(-2.0f*v0.w, -2.0f*v1.x, -2.0f*v1.y,
                             fmaf(v0.w, v0.w, fmaf(v1.x, v1.x, v1.y * v1.y)));
        dst[2] = make_float4(-2.0f*v1.z, -2.0f*v1.w, -2.0f*v2.x,
                             fmaf(v1.z, v1.z, fmaf(v1.w, v1.w, v2.x * v2.x)));
        dst[3] = make_float4(-2.0f*v2.y, -2.0f*v2.z, -2.0f*v2.w,
                             fmaf(v2.y, v2.y, fmaf(v2.z, v2.z, v2.w * v2.w)));
    }

    // Load this thread's 4 query points (before the barrier so loads overlap staging).
    float ax[QPT], ay[QPT], az[QPT], qq[QPT], m[QPT];
    int   qidx[QPT];
    #pragma unroll
    for (int k = 0; k < QPT; ++k) {
        qidx[k] = qtile * QTILE + k * TPB + threadIdx.x;
        ax[k] = qbase[qidx[k]*3+0];
        ay[k] = qbase[qidx[k]*3+1];
        az[k] = qbase[qidx[k]*3+2];
        qq[k] = fmaf(ax[k], ax[k], fmaf(ay[k], ay[k], az[k] * az[k]));
        m[k]  = 3.4e38f;
    }
    __syncthreads();

    // Inner loop: 2 refs per min update -> v_min3_f32; 3 FMA + 0.5 min per pair.
    #pragma unroll 4
    for (int j = 0; j < RCHUNK; j += 2) {
        float4 r0 = pts[j];                  // wave-uniform broadcast reads
        float4 r1 = pts[j + 1];
        #pragma unroll
        for (int k = 0; k < QPT; ++k) {
            float d0 = fmaf(r0.x, ax[k], fmaf(r0.y, ay[k], fmaf(r0.z, az[k], r0.w)));
            float d1 = fmaf(r1.x, ax[k], fmaf(r1.y, ay[k], fmaf(r1.z, az[k], r1.w)));
            m[k] = fminf(m[k], fminf(d0, d1));   // expect v_min3_f32
        }
    }

    #pragma unroll
    for (int k = 0; k < QPT; ++k) {
        // d = m + xx, clamped >= 0 so positive-float int ordering is exact for atomicMin
        float d = fmaxf(m[k] + qq[k], 0.0f);
        atomicMin(&wsmin[prob * NPTS + qidx[k]], __float_as_int(d));
    }
}

// ---------------- reduce: sum all mins -> loss ----------------
__global__ void cd_reduce(const int* __restrict__ wsmin, float* __restrict__ out) {
    float s = 0.0f;
    const int4* p = (const int4*)wsmin;
    for (int i = threadIdx.x; i < WSLEN / 4; i += 1024) {   // 16 iters, 16B/lane
        int4 v = p[i];
        s += __int_as_float(v.x) + __int_as_float(v.y)
           + __int_as_float(v.z) + __int_as_float(v.w);
    }
    for (int off = 32; off > 0; off >>= 1)
        s += __shfl_down(s, off, 64);
    __shared__ float partial[16];
    const int wave = threadIdx.x >> 6, lane = threadIdx.x & 63;
    if (lane == 0) partial[wave] = s;
    __syncthreads();
    if (threadIdx.x == 0) {
        float t = 0.0f;
        #pragma unroll
        for (int w = 0; w < 16; ++w) t += partial[w];
        out[0] = t * (0.5f / BATCH);
    }
}

extern "C" void kernel_launch(void* const* d_in, const int* in_sizes, int n_in,
                              void* d_out, int out_size, void* d_ws, size_t ws_size,
                              hipStream_t stream) {
    const float* gen   = (const float*)d_in[0];   // gen_points_batch   [4,8192,3] f32
    const float* train = (const float*)d_in[1];   // train_points_dense [4,8192,3] f32
    int*   wsmin = (int*)d_ws;                    // WSLEN ints (256 KB)
    float* out   = (float*)d_out;

    // init min slots to 0x7F7F7F7F (= 3.396e38f as float) via async memset
    hipMemsetAsync(wsmin, 0x7F, (size_t)WSLEN * sizeof(int), stream);
    dim3 grid(NQTILE, NCHUNK, NPROB);             // (4, 16, 8) = 512 blocks
    cd_chunk<<<grid, TPB, 0, stream>>>(gen, train, wsmin);
    cd_reduce<<<1, 1024, 0, stream>>>(wsmin, out);
}

// Round 3
// 32.063 us; speedup vs baseline: 2.4955x; 1.7880x over previous
//
#include <hip/hip_runtime.h>

typedef _Float16 f16x8 __attribute__((ext_vector_type(8)));
typedef float    f32x16 __attribute__((ext_vector_type(16)));

static constexpr int BATCH = 4;
static constexpr int NPTS  = 8192;
static constexpr int NPROB = 2 * BATCH;       // (batch, direction)
static constexpr int RR    = 8;               // ref ranges per problem
static constexpr int RBLK  = NPTS / RR;       // 1024 refs staged per block (16 KB LDS)
static constexpr int TPB   = 512;             // 8 waves
static constexpr int WQ    = 32;              // queries per wave (MFMA cols)
static constexpr int QBLK  = (TPB / 64) * WQ; // 256 queries per block
static constexpr int NQB   = NPTS / QBLK;     // 32

// ws layout (bytes):
//   pref  [4][2][8192] uint4  @ 0         (1 MB)  packed refs: -2x,-2y,-2z,yyhi,yylo,0,0,0 (f16)
//   pqry  [4][2][8192] uint2  @ 0x100000  (512 KB) packed queries: x,y,z,0 (f16)
//   qq    [4][2][8192] float  @ 0x180000  (256 KB) |q̂|² fp32
//   slot  [8][8192]    int    @ 0x1C0000  (256 KB) per-query min (float-as-int)

__device__ __forceinline__ unsigned packh2(_Float16 lo, _Float16 hi) {
    union { _Float16 h[2]; unsigned u; } v;
    v.h[0] = lo; v.h[1] = hi;
    return v.u;
}

// ---------------- prepack: round to f16, build MFMA-ready operands, init slots ----------------
__global__ void cd_prepack(const float* __restrict__ gen, const float* __restrict__ train,
                           uint4* __restrict__ pref, uint2* __restrict__ pqry,
                           float* __restrict__ qqv, int* __restrict__ slot) {
    const int p = blockIdx.x * 256 + threadIdx.x;   // point id within set
    const int s = blockIdx.y;                        // set: 0 = gen, 1 = train
    const int b = blockIdx.z;                        // batch
    const int idx = (b * 2 + s) * NPTS + p;          // unique in [0, 65536)
    const float* src = (s == 0 ? gen : train) + ((size_t)b * NPTS + p) * 3;
    const float x = src[0], y = src[1], z = src[2];
    const _Float16 hx = (_Float16)x, hy = (_Float16)y, hz = (_Float16)z;
    const float xr = (float)hx, yr = (float)hy, zr = (float)hz;   // exact
    const float yy = fmaf(xr, xr, fmaf(yr, yr, zr * zr));
    const _Float16 yh = (_Float16)yy;
    const _Float16 yl = (_Float16)(yy - (float)yh);               // hi/lo split
    pref[idx] = make_uint4(packh2((_Float16)(-2.0f * xr), (_Float16)(-2.0f * yr)),
                           packh2((_Float16)(-2.0f * zr), yh),
                           packh2(yl, (_Float16)0.0f), 0u);
    pqry[idx] = make_uint2(packh2(hx, hy), packh2(hz, (_Float16)0.0f));
    qqv[idx]  = yy;
    slot[idx] = 0x7F800000;                          // +inf (positive-float int order)
}

// ---------------- main: MFMA candidate distances + per-lane min3 fold ----------------
__global__ __launch_bounds__(TPB) void cd_main(const uint4* __restrict__ pref,
                                               const uint2* __restrict__ pqry,
                                               const float* __restrict__ qqv,
                                               int* __restrict__ slot) {
    __shared__ uint4 rA[RBLK];                       // 16 KB staged packed refs
    const int qb = blockIdx.x, rr = blockIdx.y, prob = blockIdx.z;
    const int b = prob >> 1, dir = prob & 1;
    const int refarr = b * 2 + (dir ^ 1);            // dir0: refs = train(set1)
    const int qarr   = b * 2 + dir;                  // dir0: queries = gen(set0)

    // stage RBLK packed refs into LDS (2 × b128 load + ds_write per thread)
    {
        const uint4* src = pref + (size_t)refarr * NPTS + rr * RBLK;
        for (int i = threadIdx.x; i < RBLK; i += TPB) rA[i] = src[i];
    }

    // B fragment: 32 queries per wave, k = [qx,qy,qz,1,1,0,0,0]; lanes>=32 all zero
    const int lane = threadIdx.x & 63, wave = threadIdx.x >> 6;
    const int qid  = qb * QBLK + wave * WQ + (lane & 31);
    const uint2 qv = pqry[(size_t)qarr * NPTS + qid];
    union { uint4 u; f16x8 h; } B;
    if (lane < 32) {
        B.u = make_uint4(qv.x, (qv.y & 0xFFFFu) | 0x3C000000u, 0x3C00u, 0u);
    } else {
        B.u = make_uint4(0u, 0u, 0u, 0u);
    }
    __syncthreads();

    // inner loop: 1 ds_read_b128 + 1 mfma + 8 min3 per 32x32 pair-tile
    float m = 3.4e38f;
    const int c = lane & 31;                         // A row index within tile (all 64 lanes;
                                                     // hi-lane A values multiplied by B=0)
    const f32x16 zc = {};
    #pragma unroll 4
    for (int t = 0; t < RBLK / 32; ++t) {            // 32 tiles
        union { uint4 u; f16x8 h; } A;
        A.u = rA[t * 32 + c];
        f32x16 d = __builtin_amdgcn_mfma_f32_32x32x16_f16(A.h, B.h, zc, 0, 0, 0);
        m = fminf(fminf(d[0],  d[1]),  m);
        m = fminf(fminf(d[2],  d[3]),  m);
        m = fminf(fminf(d[4],  d[5]),  m);
        m = fminf(fminf(d[6],  d[7]),  m);
        m = fminf(fminf(d[8],  d[9]),  m);
        m = fminf(fminf(d[10], d[11]), m);
        m = fminf(fminf(d[12], d[13]), m);
        m = fminf(fminf(d[14], d[15]), m);
    }

    // combine the two 16-row halves (lane l and l^32 cover complementary ref rows)
    m = fminf(m, __shfl_xor(m, 32));
    if (lane < 32) {
        const float dq = fmaxf(m + qqv[(size_t)qarr * NPTS + qid], 0.0f);
        atomicMin(&slot[prob * NPTS + qid], __float_as_int(dq));
    }
}

// ---------------- reduce: deterministic sum of all mins -> loss ----------------
__global__ void cd_reduce(const int* __restrict__ wsmin, float* __restrict__ out) {
    float s = 0.0f;
    const int4* p = (const int4*)wsmin;
    for (int i = threadIdx.x; i < (NPROB * NPTS) / 4; i += 1024) {
        int4 v = p[i];
        s += __int_as_float(v.x) + __int_as_float(v.y)
           + __int_as_float(v.z) + __int_as_float(v.w);
    }
    for (int off = 32; off > 0; off >>= 1)
        s += __shfl_down(s, off, 64);
    __shared__ float partial[16];
    const int wave = threadIdx.x >> 6, lane = threadIdx.x & 63;
    if (lane == 0) partial[wave] = s;
    __syncthreads();
    if (threadIdx.x == 0) {
        float t = 0.0f;
        #pragma unroll
        for (int w = 0; w < 16; ++w) t += partial[w];
        out[0] = t * (0.5f / BATCH);
    }
}

extern "C" void kernel_launch(void* const* d_in, const int* in_sizes, int n_in,
                              void* d_out, int out_size, void* d_ws, size_t ws_size,
                              hipStream_t stream) {
    const float* gen   = (const float*)d_in[0];
    const float* train = (const float*)d_in[1];
    char* ws = (char*)d_ws;
    uint4* pref = (uint4*)(ws);
    uint2* pqry = (uint2*)(ws + 0x100000);
    float* qq   = (float*)(ws + 0x180000);
    int*   slot = (int*)  (ws + 0x1C0000);
    float* out  = (float*)d_out;

    cd_prepack<<<dim3(NPTS / 256, 2, BATCH), 256, 0, stream>>>(gen, train, pref, pqry, qq, slot);
    cd_main<<<dim3(NQB, RR, NPROB), TPB, 0, stream>>>(pref, pqry, qq, slot);
    cd_reduce<<<1, 1024, 0, stream>>>(slot, out);
}